// Round 3
// baseline (195.861 us; speedup 1.0000x reference)
//
#include <hip/hip_runtime.h>
#include <stdint.h>

#define Bdim 8
#define Tdim 1024
#define Cdim 768
#define Hdim 12
#define HDdim 64
#define NROW (Bdim*Tdim)   // 8192

typedef __attribute__((ext_vector_type(8))) short s16x8;
typedef __attribute__((ext_vector_type(8))) unsigned short u16x8;
typedef __attribute__((ext_vector_type(4))) unsigned short u16x4;
typedef __attribute__((ext_vector_type(4))) float f32x4;

__device__ __forceinline__ unsigned short f2bf(float f) {
  union { float f; uint32_t u; } c; c.f = f;
  uint32_t r = (c.u + 0x7FFFu + ((c.u >> 16) & 1u)) >> 16;
  return (unsigned short)r;
}

__device__ __forceinline__ void gload16(const void* g, void* l) {
  __builtin_amdgcn_global_load_lds(
      (const __attribute__((address_space(1))) unsigned int*)g,
      (__attribute__((address_space(3))) unsigned int*)l, 16, 0, 0);
}

// ---------------- mask parse: query_mask (bool/int32/f32) -> float 0/1 -------
__global__ __launch_bounds__(256) void mask_parse(const void* __restrict__ qm,
                                                  float* __restrict__ kvm) {
  unsigned w0 = *(const unsigned*)qm;
  int idx = blockIdx.x * 256 + threadIdx.x;  // 0..8191
  float v;
  if (w0 == 0x01010101u)       v = ((const unsigned char*)qm)[idx] ? 1.f : 0.f;
  else if (w0 == 0x3F800000u)  v = (((const float*)qm)[idx] != 0.f) ? 1.f : 0.f;
  else                         v = (((const int*)qm)[idx] != 0) ? 1.f : 0.f;
  kvm[idx] = v;
}

// ---------------- f32 -> bf16 elementwise ------------------------------------
__global__ __launch_bounds__(256) void cvt_f32_bf16(const float* __restrict__ in,
                                                    unsigned short* __restrict__ out,
                                                    int n) {
  int i = (blockIdx.x * 256 + threadIdx.x) * 4;
  if (i + 3 < n) {
    float4 v = *(const float4*)&in[i];
    out[i+0] = f2bf(v.x); out[i+1] = f2bf(v.y);
    out[i+2] = f2bf(v.z); out[i+3] = f2bf(v.w);
  }
}

// ---------------- transpose + convert: in K x N f32 -> out N x K bf16 --------
__global__ __launch_bounds__(256) void transpose_cvt(const float* __restrict__ in,
                                                     unsigned short* __restrict__ out,
                                                     int K, int N) {
  __shared__ float tile[32][33];
  int n0 = blockIdx.x * 32, k0 = blockIdx.y * 32;
  int tx = threadIdx.x, ty = threadIdx.y;  // 32 x 8
  #pragma unroll
  for (int i = 0; i < 4; i++)
    tile[ty + i*8][tx] = in[(size_t)(k0 + ty + i*8) * N + n0 + tx];
  __syncthreads();
  #pragma unroll
  for (int i = 0; i < 4; i++)
    out[(size_t)(n0 + ty + i*8) * K + k0 + tx] = f2bf(tile[tx][ty + i*8]);
}

// ---------------- bf16 MFMA GEMM, A (Mx768) @ BT^T (768xN), 128x128 tile -----
// Staging via global_load_lds width=16 (m97 pattern).
// MODE 0: QKV epilogue (+bias, split: Q(*0.125) [B,H,T,64], K [B,H,T,64],
//                       V TRANSPOSED as [B,H,64,T])
// MODE 1: proj epilogue (+bias, fp32 out)
template<int MODE>
__global__ __launch_bounds__(256) void gemm_bt(
    const unsigned short* __restrict__ A,    // M x 768 bf16 row-major
    const unsigned short* __restrict__ BT,   // N x 768 bf16 row-major
    const float* __restrict__ bias,          // N
    unsigned short* __restrict__ Qo, unsigned short* __restrict__ Ko,
    unsigned short* __restrict__ Vo,
    float* __restrict__ Out) {
  __shared__ unsigned short As[128 * 32];
  __shared__ unsigned short Bs[128 * 32];
  const int K = 768;
  int m0 = blockIdx.x * 128, n0 = blockIdx.y * 128;
  int tid = threadIdx.x;
  int lane = tid & 63, wv = tid >> 6;
  int wr = wv >> 1, wc = wv & 1;
  int l16 = lane & 15, g = lane >> 4;
  f32x4 acc[4][4];
  #pragma unroll
  for (int m = 0; m < 4; m++)
    #pragma unroll
    for (int n = 0; n < 4; n++) acc[m][n] = (f32x4){0.f, 0.f, 0.f, 0.f};

  int o = tid * 16;          // byte offset: wave base + lane*16 (linear)
  int r0 = o >> 6;           // row 0..63
  int kb2 = (o & 63) >> 1;   // ushort col offset 0,8,16,24

  for (int k0 = 0; k0 < K; k0 += 32) {
    __syncthreads();
    gload16(&A [(size_t)(m0 +      r0) * K + k0 + kb2], (char*)As + o);
    gload16(&A [(size_t)(m0 + 64 + r0) * K + k0 + kb2], (char*)As + 4096 + o);
    gload16(&BT[(size_t)(n0 +      r0) * K + k0 + kb2], (char*)Bs + o);
    gload16(&BT[(size_t)(n0 + 64 + r0) * K + k0 + kb2], (char*)Bs + 4096 + o);
    __syncthreads();
    s16x8 af[4], bfr[4];
    #pragma unroll
    for (int m = 0; m < 4; m++)
      af[m] = *(const s16x8*)((const char*)As + ((wr*64 + m*16 + l16) * 64 + g*16));
    #pragma unroll
    for (int n = 0; n < 4; n++)
      bfr[n] = *(const s16x8*)((const char*)Bs + ((wc*64 + n*16 + l16) * 64 + g*16));
    __builtin_amdgcn_s_setprio(1);
    #pragma unroll
    for (int m = 0; m < 4; m++)
      #pragma unroll
      for (int n = 0; n < 4; n++)
        acc[m][n] = __builtin_amdgcn_mfma_f32_16x16x32_bf16(af[m], bfr[n], acc[m][n], 0, 0, 0);
    __builtin_amdgcn_s_setprio(0);
  }

  #pragma unroll
  for (int m = 0; m < 4; m++) {
    int row = m0 + wr*64 + m*16 + g*4;
    #pragma unroll
    for (int n = 0; n < 4; n++) {
      int col = n0 + wc*64 + n*16 + l16;
      float bv = bias[col];
      #pragma unroll
      for (int q = 0; q < 4; q++) {
        float v = acc[m][n][q] + bv;
        int rr = row + q;
        if (MODE == 0) {
          int which = col / 768;
          int cc = col - which * 768;
          int hh = cc >> 6, d = cc & 63;
          int bb = rr >> 10, t = rr & 1023;
          if (which == 0)
            Qo[(((size_t)bb * Hdim + hh) * Tdim + t) * HDdim + d] = f2bf(v * 0.125f);
          else if (which == 1)
            Ko[(((size_t)bb * Hdim + hh) * Tdim + t) * HDdim + d] = f2bf(v);
          else  // V transposed: [B,H,64,T]
            Vo[(((size_t)bb * Hdim + hh) * HDdim + d) * Tdim + t] = f2bf(v);
        } else {
          Out[(size_t)rr * 768 + col] = v;
        }
      }
    }
  }
}

// ---------------- MFMA flash attention, barrier-free, balanced ---------------
// 16 q-tiles of 64 rows; block z pairs tiles {z, 15-z} -> constant 34
// wave-tiles/block. Waves 0,1 -> tile z (32 rows each), waves 2,3 -> 15-z.
// K/V/kvm read directly from global (L2-resident per head, XCD-grouped).
// Only per-wave P-transpose buffer in LDS. No __syncthreads anywhere.
__global__ __launch_bounds__(256) void attn_mfma(
    const unsigned short* __restrict__ Qb,  // [B,H,T,64]  (pre-scaled by 0.125)
    const unsigned short* __restrict__ Kb,  // [B,H,T,64]
    const unsigned short* __restrict__ Vt,  // [B,H,64,T]
    const float* __restrict__ kvm,          // [B*T] 0/1
    unsigned short* __restrict__ attout) {  // [B*T, 768] bf16
  __shared__ unsigned short Ps[4][32 * 64]; // per-wave, swizzled [q][k]

  const int f = blockIdx.x;                 // f%8 == (h,b)%8 -> head stays on one XCD
  const int z = f / 96;                     // 0..7
  const int hb = f - z * 96;                // 0..95
  const int h = hb % Hdim, b = hb / Hdim;
  const int tid = threadIdx.x;
  const int lane = tid & 63, w = tid >> 6;
  const int l16 = lane & 15, g = lane >> 4;
  const int qt = (w < 2) ? z : (15 - z);    // this wave's 64-row q-tile
  const int q0w = qt * 64 + (w & 1) * 32;   // this wave's 32 q-rows
  const size_t head = ((size_t)b * Hdim + h) * Tdim;
  const unsigned short* qh = Qb + head * 64;
  const unsigned short* kh = Kb + head * 64;
  const unsigned short* vh = Vt + head * 64;
  const float* kvb = kvm + b * Tdim;
  const int swz = (l16 & 7) << 4;

  // Q fragments: q = q0w + jt*16 + l16, d = kc*32 + g*8 + j
  s16x8 qf[2][2];
  #pragma unroll
  for (int jt = 0; jt < 2; jt++)
    #pragma unroll
    for (int kc = 0; kc < 2; kc++)
      qf[jt][kc] = *(const s16x8*)&qh[(size_t)(q0w + jt*16 + l16) * 64 + kc*32 + g*8];

  float m_r[2] = {-1e30f, -1e30f};
  float l_r[2] = {0.f, 0.f};
  f32x4 oacc[2][4];
  #pragma unroll
  for (int mt = 0; mt < 2; mt++)
    #pragma unroll
    for (int nt = 0; nt < 4; nt++) oacc[mt][nt] = (f32x4){0.f, 0.f, 0.f, 0.f};

  for (int kt = 0; kt <= qt; kt++) {
    const int kv0 = kt * 64;

    // ---- S^T = K . Q^T : lane holds k = kv0+it*16+g*4+reg, q = q0w+jt*16+l16
    f32x4 st[4][2];
    #pragma unroll
    for (int it = 0; it < 4; it++)
      #pragma unroll
      for (int jt = 0; jt < 2; jt++) st[it][jt] = (f32x4){0.f, 0.f, 0.f, 0.f};
    #pragma unroll
    for (int kc = 0; kc < 2; kc++) {
      s16x8 kf[4];
      #pragma unroll
      for (int it = 0; it < 4; it++)
        kf[it] = *(const s16x8*)&kh[(size_t)(kv0 + it*16 + l16) * 64 + kc*32 + g*8];
      __builtin_amdgcn_s_setprio(1);
      #pragma unroll
      for (int it = 0; it < 4; it++)
        #pragma unroll
        for (int jt = 0; jt < 2; jt++)
          st[it][jt] = __builtin_amdgcn_mfma_f32_16x16x32_bf16(kf[it], qf[jt][kc], st[it][jt], 0, 0, 0);
      __builtin_amdgcn_s_setprio(0);
    }

    // key-valid per (it,reg) straight from global (L2/L1 hit)
    float kvq[4][4];
    #pragma unroll
    for (int it = 0; it < 4; it++) {
      float4 kq = *(const float4*)&kvb[kv0 + it*16 + g*4];
      kvq[it][0] = kq.x; kvq[it][1] = kq.y; kvq[it][2] = kq.z; kvq[it][3] = kq.w;
    }

    float scjt[2];
    #pragma unroll
    for (int jt = 0; jt < 2; jt++) {
      const int qg = q0w + jt*16 + l16;
      float pmax = -1e30f;
      #pragma unroll
      for (int it = 0; it < 4; it++)
        #pragma unroll
        for (int reg = 0; reg < 4; reg++) {
          int kg = kv0 + it*16 + g*4 + reg;
          float s = (kg <= qg && kvq[it][reg] > 0.f) ? st[it][jt][reg] : -1e30f;
          st[it][jt][reg] = s;
          pmax = fmaxf(pmax, s);
        }
      pmax = fmaxf(pmax, __shfl_xor(pmax, 16));
      pmax = fmaxf(pmax, __shfl_xor(pmax, 32));
      float mnew = fmaxf(m_r[jt], pmax);
      float sc = __expf(m_r[jt] - mnew);
      m_r[jt] = mnew;
      scjt[jt] = sc;
      float psum = 0.f;
      u16x4 pw[4];
      #pragma unroll
      for (int it = 0; it < 4; it++)
        #pragma unroll
        for (int reg = 0; reg < 4; reg++) {
          float p = __expf(st[it][jt][reg] - mnew);  // masked -> 0
          psum += p;
          pw[it][reg] = f2bf(p);
        }
      psum += __shfl_xor(psum, 16);
      psum += __shfl_xor(psum, 32);
      l_r[jt] = l_r[jt] * sc + psum;
      const int prow = jt*16 + l16;
      #pragma unroll
      for (int it = 0; it < 4; it++)
        *(u16x4*)((char*)Ps[w] + ((prow*128 + it*32 + g*8) ^ swz)) = pw[it];
    }

    // rescale O: rows q = mt*16 + g*4 + reg; scale lives on lanes l16 = q&15
    #pragma unroll
    for (int mt = 0; mt < 2; mt++)
      #pragma unroll
      for (int reg = 0; reg < 4; reg++) {
        float s = __shfl(scjt[mt], (lane & 48) | (g*4 + reg));
        #pragma unroll
        for (int nt = 0; nt < 4; nt++) oacc[mt][nt][reg] *= s;
      }

    // ---- PV: O += P . V  (A = P from LDS, B-frag = V^T direct from global)
    #pragma unroll
    for (int kc = 0; kc < 2; kc++) {
      s16x8 pa[2], vf[4];
      #pragma unroll
      for (int mt = 0; mt < 2; mt++) {
        int row = mt*16 + l16;
        pa[mt] = *(const s16x8*)((const char*)Ps[w] + ((row*128 + kc*64 + g*16) ^ swz));
      }
      #pragma unroll
      for (int nt = 0; nt < 4; nt++)
        vf[nt] = *(const s16x8*)&vh[(size_t)(nt*16 + l16) * Tdim + kv0 + kc*32 + g*8];
      __builtin_amdgcn_s_setprio(1);
      #pragma unroll
      for (int mt = 0; mt < 2; mt++)
        #pragma unroll
        for (int nt = 0; nt < 4; nt++)
          oacc[mt][nt] = __builtin_amdgcn_mfma_f32_16x16x32_bf16(pa[mt], vf[nt], oacc[mt][nt], 0, 0, 0);
      __builtin_amdgcn_s_setprio(0);
    }
  }

  // epilogue: normalize by l, apply query mask, write bf16
  float iv[2];
  #pragma unroll
  for (int jt = 0; jt < 2; jt++) {
    int qg = q0w + jt*16 + l16;
    float qmv = kvb[qg];
    iv[jt] = (qmv > 0.f && l_r[jt] > 0.f) ? (1.f / l_r[jt]) : 0.f;
  }
  #pragma unroll
  for (int mt = 0; mt < 2; mt++)
    #pragma unroll
    for (int reg = 0; reg < 4; reg++) {
      float ivv = __shfl(iv[mt], (lane & 48) | (g*4 + reg));
      int qg = q0w + mt*16 + g*4 + reg;
      unsigned short* op = &attout[(size_t)(b * Tdim + qg) * 768 + h * 64];
      #pragma unroll
      for (int nt = 0; nt < 4; nt++)
        op[nt*16 + l16] = f2bf(oacc[mt][nt][reg] * ivv);
    }
}

extern "C" void kernel_launch(void* const* d_in, const int* in_sizes, int n_in,
                              void* d_out, int out_size, void* d_ws, size_t ws_size,
                              hipStream_t stream) {
  const float* x  = (const float*)d_in[0];
  const void*  qmask = d_in[2];
  const float* Wa = (const float*)d_in[3];
  const float* ba = (const float*)d_in[4];
  const float* Wp = (const float*)d_in[5];
  const float* bp = (const float*)d_in[6];
  float* out = (float*)d_out;

  char* ws = (char*)d_ws;
  unsigned short* xb  = (unsigned short*)(ws + 0);          // 8192x768 bf16
  unsigned short* WaT = (unsigned short*)(ws + 12582912);   // 2304x768 bf16
  unsigned short* WpT = (unsigned short*)(ws + 16121856);   // 768x768 bf16
  unsigned short* Qb  = (unsigned short*)(ws + 17301504);   // [B,H,T,64] bf16
  unsigned short* Kb  = (unsigned short*)(ws + 29884416);   // [B,H,T,64] bf16
  unsigned short* Vb  = (unsigned short*)(ws + 42467328);   // [B,H,64,T] bf16
  unsigned short* Ab  = (unsigned short*)(ws + 55050240);   // 8192x768 bf16
  float*          kvm = (float*)(ws + 67633152);            // 8192 f32

  mask_parse<<<32, 256, 0, stream>>>(qmask, kvm);
  cvt_f32_bf16<<<6144, 256, 0, stream>>>(x, xb, NROW * 768);
  transpose_cvt<<<dim3(72, 24), dim3(32, 8), 0, stream>>>(Wa, WaT, 768, 2304);
  transpose_cvt<<<dim3(24, 24), dim3(32, 8), 0, stream>>>(Wp, WpT, 768, 768);
  gemm_bt<0><<<dim3(64, 18), 256, 0, stream>>>(xb, WaT, ba, Qb, Kb, Vb, nullptr);
  attn_mfma<<<768, 256, 0, stream>>>(Qb, Kb, Vb, kvm, Ab);
  gemm_bt<1><<<dim3(64, 6), 256, 0, stream>>>(Ab, WpT, bp, nullptr, nullptr, nullptr, out);
}